// Round 5
// baseline (565.086 us; speedup 1.0000x reference)
//
#include <hip/hip_runtime.h>
#include <cstdint>
#include <cstddef>

#define NNODES 100000
#define NEDGES 3200000
#define NF 128

// coarse buckets: 256 nodes each
#define S1_SHIFT 8
#define S1_BW 256
#define S1_NB ((NNODES + S1_BW - 1) / S1_BW)  // 391
#define S1_CH 8192
#define S1_T 512
#define S1_GRID ((NEDGES + S1_CH - 1) / S1_CH)  // 391

typedef __attribute__((ext_vector_type(8))) short short8v;
typedef __attribute__((ext_vector_type(4))) float float4v;

static __device__ __forceinline__ uint16_t f2bf(float f) {
  uint32_t u = __float_as_uint(f);
  return (uint16_t)((u + 0x7fffu + ((u >> 16) & 1u)) >> 16);  // RNE
}
static __device__ __forceinline__ float bflo(uint32_t u) { return __uint_as_float(u << 16); }
static __device__ __forceinline__ float bfhi(uint32_t u) { return __uint_as_float(u & 0xffff0000u); }

// ============ bucket histogram (LDS-privatized) ============
#define HBLK 256
__global__ __launch_bounds__(256) void k_bhist(const int* __restrict__ recv,
                                               int* __restrict__ bcount) {
  __shared__ int h[S1_NB];
  for (int i = threadIdx.x; i < S1_NB; i += 256) h[i] = 0;
  __syncthreads();
  const int stride = HBLK * 256;
  for (int i = blockIdx.x * 256 + threadIdx.x; i < NEDGES; i += stride)
    atomicAdd(&h[recv[i] >> S1_SHIFT], 1);
  __syncthreads();
  for (int i = threadIdx.x; i < S1_NB; i += 256) {
    int v = h[i];
    if (v) atomicAdd(&bcount[i], v);
  }
}

// ============ bucket exclusive scan (single block, 391 <= 512) ============
__global__ __launch_bounds__(512) void k_bscan(const int* __restrict__ bcount,
                                               int* __restrict__ boffs,
                                               int* __restrict__ bcursor) {
  __shared__ int sd[512];
  int t = threadIdx.x;
  int v = (t < S1_NB) ? bcount[t] : 0;
  sd[t] = v;
  __syncthreads();
  for (int off = 1; off < 512; off <<= 1) {
    int x = (t >= off) ? sd[t - off] : 0;
    __syncthreads();
    sd[t] += x;
    __syncthreads();
  }
  if (t < S1_NB) {
    int o = sd[t] - v;
    boffs[t] = o;
    bcursor[t] = o;
  }
  if (t == S1_NB - 1) boffs[S1_NB] = sd[t];
}

// ============ pass 1: block-local bucket binning, direct run store ============
// LDS-stage edges, local hist, reserve global runs (1 atomic per (block,bucket)),
// then place each edge directly at gb[b]+rank. No sort, no binary search.
__global__ __launch_bounds__(S1_T, 1) void k_sort1(const int* __restrict__ send,
                                                   const int* __restrict__ recv,
                                                   const float* __restrict__ ev,
                                                   int* __restrict__ bcursor,
                                                   uint2* __restrict__ buf) {
  __shared__ uint2 sbuf[S1_CH];       // 64 KB staged edges
  __shared__ uint16_t sb_b[S1_CH];    // 16 KB bucket id per edge
  __shared__ int h[S1_NB];            // hist, then insert-cursor
  __shared__ int gb[S1_NB];           // global run base per bucket
  const int t = threadIdx.x;
  const int base = blockIdx.x * S1_CH;
  const int nb = min(S1_CH, NEDGES - base);
  for (int i = t; i < S1_NB; i += S1_T) h[i] = 0;
  __syncthreads();
  for (int i = t; i < nb; i += S1_T) {
    int s = send[base + i];
    int r = recv[base + i];
    float w = ev[base + i];
    int b = r >> S1_SHIFT;
    sbuf[i] = make_uint2((uint32_t)s | ((uint32_t)(r & (S1_BW - 1)) << 17), __float_as_uint(w));
    sb_b[i] = (uint16_t)b;
    atomicAdd(&h[b], 1);
  }
  __syncthreads();
  if (t < S1_NB) {
    int v = h[t];
    if (v) gb[t] = atomicAdd(&bcursor[t], v);
    h[t] = 0;  // reuse as cursor
  }
  __syncthreads();
  for (int i = t; i < nb; i += S1_T) {
    int b = sb_b[i];
    int rk = atomicAdd(&h[b], 1);
    buf[gb[b] + rk] = sbuf[i];
  }
}

// ============ pass 2: per-bucket sort to node granularity -> final CSR ============
__global__ __launch_bounds__(256) void k_pass2(const uint2* __restrict__ buf,
                                               const int* __restrict__ boffs,
                                               int* __restrict__ offs,
                                               int* __restrict__ counts,
                                               int2* __restrict__ csr) {
  __shared__ int hcnt[S1_BW], hoff2[S1_BW], sd[S1_BW];
  const int b = blockIdx.x, t = threadIdx.x;
  const int bstart = boffs[b], bend = boffs[b + 1];
  const int nb = bend - bstart;
  hcnt[t] = 0;
  __syncthreads();
  for (int i = t; i < nb; i += 256) atomicAdd(&hcnt[buf[bstart + i].x >> 17], 1);
  __syncthreads();
  int v = hcnt[t];
  sd[t] = v;
  __syncthreads();
  for (int off = 1; off < 256; off <<= 1) {
    int x = (t >= off) ? sd[t - off] : 0;
    __syncthreads();
    sd[t] += x;
    __syncthreads();
  }
  int excl = sd[t] - v;
  hoff2[t] = excl;
  int node = b * S1_BW + t;
  if (node < NNODES) {
    offs[node] = bstart + excl;
    counts[node] = v;
  }
  hcnt[t] = 0;
  __syncthreads();
  for (int i = t; i < nb; i += 256) {
    uint2 e = buf[bstart + i];
    uint32_t rl = e.x >> 17;
    int pos = bstart + hoff2[rl] + atomicAdd(&hcnt[rl], 1);
    csr[pos] = make_int2((int)(e.x & 0x1FFFFu), (int)e.y);
  }
}

// ============ W -> bf16, transposed [n][k] ============
__global__ __launch_bounds__(256) void k_wprep(const float* __restrict__ W1,
                                               const float* __restrict__ W2,
                                               uint16_t* __restrict__ wT) {
  const float* W = blockIdx.x ? W2 : W1;
  uint16_t* o = wT + blockIdx.x * 16384;
  for (int i = threadIdx.x; i < 16384; i += 256) {
    int k = i >> 7, n = i & 127;
    o[n * 128 + k] = f2bf(W[i]);
  }
}

// ============ MFMA bf16 GEMM: Y[N,128](bf16) = X[N,128] @ W ============
template <bool XF32>
__global__ __launch_bounds__(256) void k_gemm(const void* __restrict__ Xv,
                                              const uint16_t* __restrict__ wT,
                                              uint16_t* __restrict__ Y) {
  __shared__ uint16_t sX[64 * 128];
  __shared__ uint16_t sWT[128 * 128];  // [n][k], swizzled 16B chunks
  const int t = threadIdx.x;
  const int r0 = blockIdx.x * 64;
  {
    const uint4* src = (const uint4*)wT;
    uint4* dst = (uint4*)sWT;
#pragma unroll
    for (int j = 0; j < 8; ++j) {
      int i = j * 256 + t;
      int row = i >> 4;
      dst[(i & ~15) | ((i & 15) ^ (row & 7))] = src[i];
    }
  }
  if (XF32) {
    const float* X = (const float*)Xv;
    int r = t >> 2, c0 = (t & 3) * 32;
    int grow = r0 + r;
    if (grow >= NNODES) grow = NNODES - 1;
    const float* xp = X + (size_t)grow * 128 + c0;
    uint4* xdst = (uint4*)sX;
#pragma unroll
    for (int j = 0; j < 4; ++j) {
      float4 f0 = *(const float4*)(xp + j * 8);
      float4 f1 = *(const float4*)(xp + j * 8 + 4);
      uint4 vv;
      vv.x = (uint32_t)f2bf(f0.x) | ((uint32_t)f2bf(f0.y) << 16);
      vv.y = (uint32_t)f2bf(f0.z) | ((uint32_t)f2bf(f0.w) << 16);
      vv.z = (uint32_t)f2bf(f1.x) | ((uint32_t)f2bf(f1.y) << 16);
      vv.w = (uint32_t)f2bf(f1.z) | ((uint32_t)f2bf(f1.w) << 16);
      int kc = (c0 >> 3) + j;
      xdst[r * 16 + (kc ^ (r & 7))] = vv;
    }
  } else {
    const uint4* src = (const uint4*)((const char*)Xv + (size_t)r0 * 256);
    uint4* xdst = (uint4*)sX;
    size_t maxByte = (size_t)NNODES * 256 - (size_t)r0 * 256;
#pragma unroll
    for (int j = 0; j < 4; ++j) {
      int i = j * 256 + t;
      int row = i >> 4;
      uint4 vv = ((size_t)i * 16 < maxByte) ? src[i] : make_uint4(0, 0, 0, 0);
      xdst[(i & ~15) | ((i & 15) ^ (row & 7))] = vv;
    }
  }
  __syncthreads();
  const int l = t & 63, w = t >> 6;
  const int m16 = l & 15, kb = l >> 4;
  const int arow = w * 16 + m16;
  short8v a[4];
#pragma unroll
  for (int ks = 0; ks < 4; ++ks) {
    int elem = (ks * 32 + kb * 8) ^ ((arow & 7) << 3);
    a[ks] = *reinterpret_cast<const short8v*>(&sX[arow * 128 + elem]);
  }
  float4v acc[8] = {};
#pragma unroll
  for (int nt = 0; nt < 8; ++nt) {
    int brow = nt * 16 + m16;
    int bswz = (brow & 7) << 3;
    int bbase = brow * 128;
#pragma unroll
    for (int ks = 0; ks < 4; ++ks) {
      short8v bb = *reinterpret_cast<const short8v*>(&sWT[bbase + ((ks * 32 + kb * 8) ^ bswz)]);
      acc[nt] = __builtin_amdgcn_mfma_f32_16x16x32_bf16(a[ks], bb, acc[nt], 0, 0, 0);
    }
  }
  const int orow0 = r0 + w * 16 + kb * 4;
#pragma unroll
  for (int nt = 0; nt < 8; ++nt) {
    int col = nt * 16 + m16;
#pragma unroll
    for (int q = 0; q < 4; ++q) {
      int grow = orow0 + q;
      if (grow < NNODES) Y[(size_t)grow * 128 + col] = f2bf(acc[nt][q]);
    }
  }
}

// ============ SpMM + bias + relu: half-wave per edge, predicated uniform loop ======
// lanes 0-31 handle even edges, 32-63 odd; each lane loads 8B (4 bf16 feats) of the
// source row; cross-half combine via shfl_xor(32) at the end.
template <bool OUTBF>
__global__ __launch_bounds__(256) void k_spmm(const uint16_t* __restrict__ supp,
                                              const int2* __restrict__ csr,
                                              const int* __restrict__ offs,
                                              const int* __restrict__ counts,
                                              const float* __restrict__ bias,
                                              void* __restrict__ outp) {
  const int wid = (blockIdx.x * 256 + threadIdx.x) >> 6;
  const int lane = threadIdx.x & 63;
  if (wid >= NNODES) return;
  const int start = offs[wid], deg = counts[wid];
  const int half = lane >> 5;   // 0: even edge of pair, 1: odd
  const int fl = lane & 31;     // feature lane: feats [4fl .. 4fl+3]
  const int2* e = csr + start;
  const char* sb = (const char*)supp + fl * 8;
  float a0 = 0.f, a1 = 0.f, a2 = 0.f, a3 = 0.f;
  const int dm1 = deg - 1;
  for (int i = 0; i < deg; i += 8) {
#pragma unroll
    for (int p = 0; p < 4; ++p) {
      int idx = i + 2 * p + half;
      int2 ee = e[min(idx, dm1)];
      float v = (idx < deg) ? __int_as_float(ee.y) : 0.f;
      uint2 h8 = *reinterpret_cast<const uint2*>(sb + (size_t)ee.x * 256);
      a0 += v * bflo(h8.x);
      a1 += v * bfhi(h8.x);
      a2 += v * bflo(h8.y);
      a3 += v * bfhi(h8.y);
    }
  }
  a0 += __shfl_xor(a0, 32, 64);
  a1 += __shfl_xor(a1, 32, 64);
  a2 += __shfl_xor(a2, 32, 64);
  a3 += __shfl_xor(a3, 32, 64);
  if (half == 0) {
    float4 bv = *reinterpret_cast<const float4*>(bias + fl * 4);
    float o0 = fmaxf(a0 + bv.x, 0.f);
    float o1 = fmaxf(a1 + bv.y, 0.f);
    float o2 = fmaxf(a2 + bv.z, 0.f);
    float o3 = fmaxf(a3 + bv.w, 0.f);
    if (OUTBF) {
      uint2 pk;
      pk.x = (uint32_t)f2bf(o0) | ((uint32_t)f2bf(o1) << 16);
      pk.y = (uint32_t)f2bf(o2) | ((uint32_t)f2bf(o3) << 16);
      reinterpret_cast<uint2*>(outp)[(size_t)wid * 32 + fl] = pk;
    } else {
      *reinterpret_cast<float4*>((float*)outp + (size_t)wid * 128 + fl * 4) =
          make_float4(o0, o1, o2, o3);
    }
  }
}

// ============ launch ============
extern "C" void kernel_launch(void* const* d_in, const int* in_sizes, int n_in,
                              void* d_out, int out_size, void* d_ws, size_t ws_size,
                              hipStream_t stream) {
  const float* x = (const float*)d_in[0];
  const int* senders = (const int*)d_in[1];
  const int* recv = (const int*)d_in[2];
  const float* ev = (const float*)d_in[3];
  const float* W1 = (const float*)d_in[4];
  const float* b1 = (const float*)d_in[5];
  const float* W2 = (const float*)d_in[6];
  const float* b2 = (const float*)d_in[7];
  float* out = (float*)d_out;

  char* ws = (char*)d_ws;
  uint16_t* suppB = (uint16_t*)ws;            // 25,600,000 B  bf16 support table
  int2* csr = (int2*)(ws + 25600000);         // 25,600,000 B  final CSR (s, ev)
  char* bufB = ws + 51200000;                 // 25,600,000 B  pass1 buf, later h1 bf16
  int* offs = (int*)(ws + 76800000);          // 400,000 B
  int* counts = (int*)(ws + 77200000);        // 400,000 B
  int* bcount = (int*)(ws + 77600000);        // S1_NB ints
  int* bcursor = (int*)(ws + 77612800);       // S1_NB ints
  int* boffs = (int*)(ws + 77625600);         // S1_NB+1 ints
  uint16_t* wT = (uint16_t*)(ws + 77638400);  // 65,536 B  (end ~77.7 MB)

  hipMemsetAsync(bcount, 0, S1_NB * sizeof(int), stream);
  k_bhist<<<HBLK, 256, 0, stream>>>(recv, bcount);
  k_bscan<<<1, 512, 0, stream>>>(bcount, boffs, bcursor);
  k_sort1<<<S1_GRID, S1_T, 0, stream>>>(senders, recv, ev, bcursor, (uint2*)bufB);
  k_pass2<<<S1_NB, 256, 0, stream>>>((const uint2*)bufB, boffs, offs, counts, csr);
  k_wprep<<<2, 256, 0, stream>>>(W1, W2, wT);

  // layer 1
  k_gemm<true><<<(NNODES + 63) / 64, 256, 0, stream>>>(x, wT, suppB);
  k_spmm<true><<<(NNODES * 64) / 256, 256, 0, stream>>>(suppB, csr, offs, counts, b1, bufB);
  // layer 2
  k_gemm<false><<<(NNODES + 63) / 64, 256, 0, stream>>>(bufB, wT + 16384, suppB);
  k_spmm<false><<<(NNODES * 64) / 256, 256, 0, stream>>>(suppB, csr, offs, counts, b2, out);
}

// Round 6
// 527.181 us; speedup vs baseline: 1.0719x; 1.0719x over previous
//
#include <hip/hip_runtime.h>
#include <cstdint>
#include <cstddef>

#define NNODES 100000
#define NEDGES 3200000
#define NF 128

// coarse buckets: 256 nodes each
#define S1_SHIFT 8
#define S1_BW 256
#define S1_NB ((NNODES + S1_BW - 1) / S1_BW)  // 391
#define S1_CH 8192
#define S1_T 512
#define S1_GRID ((NEDGES + S1_CH - 1) / S1_CH)  // 391

// pass2: second-level counting sort key = local_r(8b) x sender-tile(5b)
#define T2_TILES 32                       // sender>>12 -> 0..24
#define T2_KEYS (S1_BW * T2_TILES)        // 8192
#define T2_MAXE 8960                      // bucket size mean 8184, sd ~90; 8.6 sigma headroom

typedef __attribute__((ext_vector_type(8))) short short8v;
typedef __attribute__((ext_vector_type(4))) float float4v;

static __device__ __forceinline__ uint16_t f2bf(float f) {
  uint32_t u = __float_as_uint(f);
  return (uint16_t)((u + 0x7fffu + ((u >> 16) & 1u)) >> 16);  // RNE
}
static __device__ __forceinline__ float bflo(uint32_t u) { return __uint_as_float(u << 16); }
static __device__ __forceinline__ float bfhi(uint32_t u) { return __uint_as_float(u & 0xffff0000u); }

// ============ bucket histogram (LDS-privatized) ============
#define HBLK 256
__global__ __launch_bounds__(256) void k_bhist(const int* __restrict__ recv,
                                               int* __restrict__ bcount) {
  __shared__ int h[S1_NB];
  for (int i = threadIdx.x; i < S1_NB; i += 256) h[i] = 0;
  __syncthreads();
  const int stride = HBLK * 256;
  for (int i = blockIdx.x * 256 + threadIdx.x; i < NEDGES; i += stride)
    atomicAdd(&h[recv[i] >> S1_SHIFT], 1);
  __syncthreads();
  for (int i = threadIdx.x; i < S1_NB; i += 256) {
    int v = h[i];
    if (v) atomicAdd(&bcount[i], v);
  }
}

// ============ bucket exclusive scan (single block, 391 <= 512) ============
__global__ __launch_bounds__(512) void k_bscan(const int* __restrict__ bcount,
                                               int* __restrict__ boffs,
                                               int* __restrict__ bcursor) {
  __shared__ int sd[512];
  int t = threadIdx.x;
  int v = (t < S1_NB) ? bcount[t] : 0;
  sd[t] = v;
  __syncthreads();
  for (int off = 1; off < 512; off <<= 1) {
    int x = (t >= off) ? sd[t - off] : 0;
    __syncthreads();
    sd[t] += x;
    __syncthreads();
  }
  if (t < S1_NB) {
    int o = sd[t] - v;
    boffs[t] = o;
    bcursor[t] = o;
  }
  if (t == S1_NB - 1) boffs[S1_NB] = sd[t];
}

// ============ pass 1: block-local bucket binning, direct run store ============
__global__ __launch_bounds__(S1_T, 1) void k_sort1(const int* __restrict__ send,
                                                   const int* __restrict__ recv,
                                                   const float* __restrict__ ev,
                                                   int* __restrict__ bcursor,
                                                   uint2* __restrict__ buf) {
  __shared__ uint2 sbuf[S1_CH];       // 64 KB staged edges
  __shared__ uint16_t sb_b[S1_CH];    // 16 KB bucket id per edge
  __shared__ int h[S1_NB];            // hist, then insert-cursor
  __shared__ int gb[S1_NB];           // global run base per bucket
  const int t = threadIdx.x;
  const int base = blockIdx.x * S1_CH;
  const int nb = min(S1_CH, NEDGES - base);
  for (int i = t; i < S1_NB; i += S1_T) h[i] = 0;
  __syncthreads();
  for (int i = t; i < nb; i += S1_T) {
    int s = send[base + i];
    int r = recv[base + i];
    float w = ev[base + i];
    int b = r >> S1_SHIFT;
    sbuf[i] = make_uint2((uint32_t)s | ((uint32_t)(r & (S1_BW - 1)) << 17), __float_as_uint(w));
    sb_b[i] = (uint16_t)b;
    atomicAdd(&h[b], 1);
  }
  __syncthreads();
  if (t < S1_NB) {
    int v = h[t];
    if (v) gb[t] = atomicAdd(&bcursor[t], v);
    h[t] = 0;  // reuse as cursor
  }
  __syncthreads();
  for (int i = t; i < nb; i += S1_T) {
    int b = sb_b[i];
    int rk = atomicAdd(&h[b], 1);
    buf[gb[b] + rk] = sbuf[i];
  }
}

// ============ pass 2: per-bucket sort to (node, sender-tile) -> final CSR ============
// Orders each node's edges by sender>>12 (1MB tiles) so concurrent spmm waves walk
// the support table in a moving ~1-2MB window (L2-resident per XCD).
__global__ __launch_bounds__(256) void k_pass2(const uint2* __restrict__ buf,
                                               const int* __restrict__ boffs,
                                               int* __restrict__ offs,
                                               int* __restrict__ counts,
                                               int2* __restrict__ csr) {
  __shared__ uint2 se[T2_MAXE];        // 71680 B
  __shared__ uint16_t sk[T2_MAXE];     // 17920 B
  __shared__ int hist[T2_KEYS];        // 32768 B
  __shared__ int sd[256];              // total ~123.4 KB
  const int b = blockIdx.x, t = threadIdx.x;
  const int bstart = boffs[b], bend = boffs[b + 1];
  const int nb = bend - bstart;
  for (int i = t; i < T2_KEYS; i += 256) hist[i] = 0;
  __syncthreads();
  for (int i = t; i < nb; i += 256) {
    uint2 e = buf[bstart + i];
    int lr = e.x >> 17;
    int tile = (int)((e.x & 0x1FFFFu) >> 12);
    int key = lr * T2_TILES + tile;
    se[i] = e;
    sk[i] = (uint16_t)key;
    atomicAdd(&hist[key], 1);
  }
  __syncthreads();
  // scan over 8192 keys: thread t owns node t's 32 tile-counts
  const int kbase = t * T2_TILES;
  int s = 0;
  for (int j = 0; j < T2_TILES; ++j) s += hist[kbase + j];
  sd[t] = s;
  __syncthreads();
  for (int off = 1; off < 256; off <<= 1) {
    int x = (t >= off) ? sd[t - off] : 0;
    __syncthreads();
    sd[t] += x;
    __syncthreads();
  }
  int run = sd[t] - s;
  for (int j = 0; j < T2_TILES; ++j) {
    int c = hist[kbase + j];
    hist[kbase + j] = run;
    run += c;
  }
  __syncthreads();
  {  // per-node offs/counts (key range [t*32,(t+1)*32) is exactly node t)
    int node = b * S1_BW + t;
    if (node < NNODES) {
      int o = hist[kbase];
      int nxt = (t < 255) ? hist[kbase + T2_TILES] : nb;
      offs[node] = bstart + o;
      counts[node] = nxt - o;
    }
  }
  __syncthreads();
  for (int i = t; i < nb; i += 256) {
    int key = sk[i];
    int slot = atomicAdd(&hist[key], 1);
    uint2 e = se[i];
    csr[bstart + slot] = make_int2((int)(e.x & 0x1FFFFu), (int)e.y);
  }
}

// ============ W -> bf16, transposed [n][k] ============
__global__ __launch_bounds__(256) void k_wprep(const float* __restrict__ W1,
                                               const float* __restrict__ W2,
                                               uint16_t* __restrict__ wT) {
  const float* W = blockIdx.x ? W2 : W1;
  uint16_t* o = wT + blockIdx.x * 16384;
  for (int i = threadIdx.x; i < 16384; i += 256) {
    int k = i >> 7, n = i & 127;
    o[n * 128 + k] = f2bf(W[i]);
  }
}

// ============ MFMA bf16 GEMM: Y[N,128](bf16) = X[N,128] @ W ============
template <bool XF32>
__global__ __launch_bounds__(256) void k_gemm(const void* __restrict__ Xv,
                                              const uint16_t* __restrict__ wT,
                                              uint16_t* __restrict__ Y) {
  __shared__ uint16_t sX[64 * 128];
  __shared__ uint16_t sWT[128 * 128];  // [n][k], swizzled 16B chunks
  const int t = threadIdx.x;
  const int r0 = blockIdx.x * 64;
  {
    const uint4* src = (const uint4*)wT;
    uint4* dst = (uint4*)sWT;
#pragma unroll
    for (int j = 0; j < 8; ++j) {
      int i = j * 256 + t;
      int row = i >> 4;
      dst[(i & ~15) | ((i & 15) ^ (row & 7))] = src[i];
    }
  }
  if (XF32) {
    const float* X = (const float*)Xv;
    int r = t >> 2, c0 = (t & 3) * 32;
    int grow = r0 + r;
    if (grow >= NNODES) grow = NNODES - 1;
    const float* xp = X + (size_t)grow * 128 + c0;
    uint4* xdst = (uint4*)sX;
#pragma unroll
    for (int j = 0; j < 4; ++j) {
      float4 f0 = *(const float4*)(xp + j * 8);
      float4 f1 = *(const float4*)(xp + j * 8 + 4);
      uint4 vv;
      vv.x = (uint32_t)f2bf(f0.x) | ((uint32_t)f2bf(f0.y) << 16);
      vv.y = (uint32_t)f2bf(f0.z) | ((uint32_t)f2bf(f0.w) << 16);
      vv.z = (uint32_t)f2bf(f1.x) | ((uint32_t)f2bf(f1.y) << 16);
      vv.w = (uint32_t)f2bf(f1.z) | ((uint32_t)f2bf(f1.w) << 16);
      int kc = (c0 >> 3) + j;
      xdst[r * 16 + (kc ^ (r & 7))] = vv;
    }
  } else {
    const uint4* src = (const uint4*)((const char*)Xv + (size_t)r0 * 256);
    uint4* xdst = (uint4*)sX;
    size_t maxByte = (size_t)NNODES * 256 - (size_t)r0 * 256;
#pragma unroll
    for (int j = 0; j < 4; ++j) {
      int i = j * 256 + t;
      int row = i >> 4;
      uint4 vv = ((size_t)i * 16 < maxByte) ? src[i] : make_uint4(0, 0, 0, 0);
      xdst[(i & ~15) | ((i & 15) ^ (row & 7))] = vv;
    }
  }
  __syncthreads();
  const int l = t & 63, w = t >> 6;
  const int m16 = l & 15, kb = l >> 4;
  const int arow = w * 16 + m16;
  short8v a[4];
#pragma unroll
  for (int ks = 0; ks < 4; ++ks) {
    int elem = (ks * 32 + kb * 8) ^ ((arow & 7) << 3);
    a[ks] = *reinterpret_cast<const short8v*>(&sX[arow * 128 + elem]);
  }
  float4v acc[8] = {};
#pragma unroll
  for (int nt = 0; nt < 8; ++nt) {
    int brow = nt * 16 + m16;
    int bswz = (brow & 7) << 3;
    int bbase = brow * 128;
#pragma unroll
    for (int ks = 0; ks < 4; ++ks) {
      short8v bb = *reinterpret_cast<const short8v*>(&sWT[bbase + ((ks * 32 + kb * 8) ^ bswz)]);
      acc[nt] = __builtin_amdgcn_mfma_f32_16x16x32_bf16(a[ks], bb, acc[nt], 0, 0, 0);
    }
  }
  const int orow0 = r0 + w * 16 + kb * 4;
#pragma unroll
  for (int nt = 0; nt < 8; ++nt) {
    int col = nt * 16 + m16;
#pragma unroll
    for (int q = 0; q < 4; ++q) {
      int grow = orow0 + q;
      if (grow < NNODES) Y[(size_t)grow * 128 + col] = f2bf(acc[nt][q]);
    }
  }
}

// ============ SpMM + bias + relu (bf16 gather, 4B/lane, predicated tail) ============
template <bool OUTBF>
__global__ __launch_bounds__(256) void k_spmm(const uint32_t* __restrict__ suppB,
                                              const int2* __restrict__ csr,
                                              const int* __restrict__ offs,
                                              const int* __restrict__ counts,
                                              const float* __restrict__ bias,
                                              void* __restrict__ outp) {
  const int wid = (blockIdx.x * 256 + threadIdx.x) >> 6;
  const int lane = threadIdx.x & 63;
  if (wid >= NNODES) return;
  const int start = offs[wid], deg = counts[wid];
  const int2* e = csr + start;
  const uint32_t* sb = suppB + lane;
  float ax = 0.f, ay = 0.f;
  int i = 0;
  for (; i + 8 <= deg; i += 8) {
    int2 e0 = e[i], e1 = e[i + 1], e2 = e[i + 2], e3 = e[i + 3];
    int2 e4 = e[i + 4], e5 = e[i + 5], e6 = e[i + 6], e7 = e[i + 7];
    uint32_t h0 = sb[(size_t)e0.x * 64];
    uint32_t h1 = sb[(size_t)e1.x * 64];
    uint32_t h2 = sb[(size_t)e2.x * 64];
    uint32_t h3 = sb[(size_t)e3.x * 64];
    uint32_t h4 = sb[(size_t)e4.x * 64];
    uint32_t h5 = sb[(size_t)e5.x * 64];
    uint32_t h6 = sb[(size_t)e6.x * 64];
    uint32_t h7 = sb[(size_t)e7.x * 64];
    float v0 = __int_as_float(e0.y), v1 = __int_as_float(e1.y);
    float v2 = __int_as_float(e2.y), v3 = __int_as_float(e3.y);
    float v4 = __int_as_float(e4.y), v5 = __int_as_float(e5.y);
    float v6 = __int_as_float(e6.y), v7 = __int_as_float(e7.y);
    ax += v0 * bflo(h0); ay += v0 * bfhi(h0);
    ax += v1 * bflo(h1); ay += v1 * bfhi(h1);
    ax += v2 * bflo(h2); ay += v2 * bfhi(h2);
    ax += v3 * bflo(h3); ay += v3 * bfhi(h3);
    ax += v4 * bflo(h4); ay += v4 * bfhi(h4);
    ax += v5 * bflo(h5); ay += v5 * bfhi(h5);
    ax += v6 * bflo(h6); ay += v6 * bfhi(h6);
    ax += v7 * bflo(h7); ay += v7 * bfhi(h7);
  }
  if (i < deg) {  // predicated tail: up to 8 parallel clamped loads, zeroed weights
    const int dm1 = deg - 1;
#pragma unroll
    for (int p = 0; p < 8; ++p) {
      int idx = i + p;
      int2 ee = e[min(idx, dm1)];
      float v = (idx < deg) ? __int_as_float(ee.y) : 0.f;
      uint32_t h = sb[(size_t)ee.x * 64];
      ax += v * bflo(h);
      ay += v * bfhi(h);
    }
  }
  float bx = bias[lane * 2], by = bias[lane * 2 + 1];
  float ox = fmaxf(ax + bx, 0.f), oy = fmaxf(ay + by, 0.f);
  if (OUTBF) {
    ((uint32_t*)outp)[(size_t)wid * 64 + lane] = (uint32_t)f2bf(ox) | ((uint32_t)f2bf(oy) << 16);
  } else {
    *reinterpret_cast<float2*>((float*)outp + (size_t)wid * 128 + lane * 2) = make_float2(ox, oy);
  }
}

// ============ launch ============
extern "C" void kernel_launch(void* const* d_in, const int* in_sizes, int n_in,
                              void* d_out, int out_size, void* d_ws, size_t ws_size,
                              hipStream_t stream) {
  const float* x = (const float*)d_in[0];
  const int* senders = (const int*)d_in[1];
  const int* recv = (const int*)d_in[2];
  const float* ev = (const float*)d_in[3];
  const float* W1 = (const float*)d_in[4];
  const float* b1 = (const float*)d_in[5];
  const float* W2 = (const float*)d_in[6];
  const float* b2 = (const float*)d_in[7];
  float* out = (float*)d_out;

  char* ws = (char*)d_ws;
  uint16_t* suppB = (uint16_t*)ws;            // 25,600,000 B  bf16 support table
  int2* csr = (int2*)(ws + 25600000);         // 25,600,000 B  final CSR (s, ev)
  char* bufB = ws + 51200000;                 // 25,600,000 B  pass1 buf, later h1 bf16
  int* offs = (int*)(ws + 76800000);          // 400,000 B
  int* counts = (int*)(ws + 77200000);        // 400,000 B
  int* bcount = (int*)(ws + 77600000);        // S1_NB ints
  int* bcursor = (int*)(ws + 77612800);       // S1_NB ints
  int* boffs = (int*)(ws + 77625600);         // S1_NB+1 ints
  uint16_t* wT = (uint16_t*)(ws + 77638400);  // 65,536 B  (end ~77.7 MB)

  hipMemsetAsync(bcount, 0, S1_NB * sizeof(int), stream);
  k_bhist<<<HBLK, 256, 0, stream>>>(recv, bcount);
  k_bscan<<<1, 512, 0, stream>>>(bcount, boffs, bcursor);
  k_sort1<<<S1_GRID, S1_T, 0, stream>>>(senders, recv, ev, bcursor, (uint2*)bufB);
  k_pass2<<<S1_NB, 256, 0, stream>>>((const uint2*)bufB, boffs, offs, counts, csr);
  k_wprep<<<2, 256, 0, stream>>>(W1, W2, wT);

  // layer 1
  k_gemm<true><<<(NNODES + 63) / 64, 256, 0, stream>>>(x, wT, suppB);
  k_spmm<true><<<(NNODES * 64) / 256, 256, 0, stream>>>((const uint32_t*)suppB, csr, offs,
                                                        counts, b1, bufB);
  // layer 2
  k_gemm<false><<<(NNODES + 63) / 64, 256, 0, stream>>>(bufB, wT + 16384, suppB);
  k_spmm<false><<<(NNODES * 64) / 256, 256, 0, stream>>>((const uint32_t*)suppB, csr, offs,
                                                         counts, b2, out);
}